// Round 15
// baseline (276.956 us; speedup 1.0000x reference)
//
#include <hip/hip_runtime.h>

typedef _Float16 f16;
typedef f16  f16x8 __attribute__((ext_vector_type(8)));
typedef f16  f16x4 __attribute__((ext_vector_type(4)));
typedef float f32x4 __attribute__((ext_vector_type(4)));

#define DIM_   2048
#define SEQ_   2048
#define BATCH_ 2
#define MROWS_ (BATCH_*SEQ_)   // 4096
#define HD_    64
#define KVW_   512             // k (or v) projection width

__device__ __forceinline__ f32x4 mfma16(f16x8 a, f16x8 b, f32x4 c) {
  return __builtin_amdgcn_mfma_f32_16x16x32_f16(a, b, c, 0, 0, 0);
}

// async global->LDS, 16B per lane; LDS dest is wave-uniform base + lane*16
typedef const __attribute__((address_space(1))) void gas_void;
typedef __attribute__((address_space(3))) void las_void;
__device__ __forceinline__ void gload16(const void* g, void* l) {
  __builtin_amdgcn_global_load_lds((gas_void*)g, (las_void*)l, 16, 0, 0);
}

// pack 4 f32 -> 4 f16 (RTZ) as one 8B word for ds_write_b64
__device__ __forceinline__ unsigned long long pk4(float a, float b, float c, float d) {
  union { _Float16 h[4]; unsigned long long u; } z;
  auto p0 = __builtin_amdgcn_cvt_pkrtz(a, b);
  auto p1 = __builtin_amdgcn_cvt_pkrtz(c, d);
  z.h[0] = p0[0]; z.h[1] = p0[1]; z.h[2] = p1[0]; z.h[3] = p1[1];
  return z.u;
}

// ---------------- prep1: |w| per-block partials (y=0..3) + x hi/lo split
// (y=4..5).  NO atomics: fixed orders everywhere -> replay-deterministic.
__global__ __launch_bounds__(256)
void prep1(const float* __restrict__ x,
           const float* __restrict__ w0, const float* __restrict__ w1,
           const float* __restrict__ w2, const float* __restrict__ w3,
           float* __restrict__ parts, f16* __restrict__ hi, f16* __restrict__ lo) {
  const int id = blockIdx.y;
  if (id < 4) {
    const float* w = id == 0 ? w0 : id == 1 ? w1 : id == 2 ? w2 : w3;
    const int n4 = (id == 1 || id == 2) ? (KVW_ * DIM_ / 4) : (DIM_ * DIM_ / 4);
    float s = 0.f;
    for (int i = blockIdx.x * 256 + threadIdx.x; i < n4; i += gridDim.x * 256) {
      float4 v = *(const float4*)(w + (long)i * 4);
      s += fabsf(v.x) + fabsf(v.y) + fabsf(v.z) + fabsf(v.w);
    }
    #pragma unroll
    for (int off = 32; off > 0; off >>= 1)
      s += __shfl_down(s, off, 64);
    __shared__ float red[4];
    int lane = threadIdx.x & 63, wv = threadIdx.x >> 6;
    if (lane == 0) red[wv] = s;
    __syncthreads();
    if (threadIdx.x == 0)
      parts[id * 192 + blockIdx.x] = (red[0] + red[1]) + (red[2] + red[3]);
  } else {
    const int half = (MROWS_ * DIM_ / 4) / 2;
    const long base = (long)(id - 4) * half;
    for (int i = blockIdx.x * 256 + threadIdx.x; i < half; i += gridDim.x * 256) {
      float4 v = *(const float4*)(x + (base + i) * 4);
      f16x4 h, l;
      h[0] = (f16)v.x; l[0] = (f16)(v.x - (float)h[0]);
      h[1] = (f16)v.y; l[1] = (f16)(v.y - (float)h[1]);
      h[2] = (f16)v.z; l[2] = (f16)(v.z - (float)h[2]);
      h[3] = (f16)v.w; l[3] = (f16)(v.w - (float)h[3]);
      *(f16x4*)(hi + (base + i) * 4) = h;
      *(f16x4*)(lo + (base + i) * 4) = l;
    }
  }
}

// ---------------- ternarize (inline deterministic final reduce) -------------
__global__ __launch_bounds__(256)
void ternarize4(const float* __restrict__ w0, const float* __restrict__ w1,
                const float* __restrict__ w2, const float* __restrict__ w3,
                unsigned short* __restrict__ t0, unsigned short* __restrict__ t1,
                unsigned short* __restrict__ t2, unsigned short* __restrict__ t3,
                const float* __restrict__ parts) {
  const int id = blockIdx.y;
  const float* w = id == 0 ? w0 : id == 1 ? w1 : id == 2 ? w2 : w3;
  unsigned short* t = id == 0 ? t0 : id == 1 ? t1 : id == 2 ? t2 : t3;
  const int n = (id == 1 || id == 2) ? (KVW_ * DIM_) : (DIM_ * DIM_);

  __shared__ float thr_s;
  if (threadIdx.x < 64) {
    const int lane = threadIdx.x;
    float s = parts[id * 192 + lane] + parts[id * 192 + 64 + lane]
            + parts[id * 192 + 128 + lane];
    #pragma unroll
    for (int off = 32; off > 0; off >>= 1)
      s += __shfl_down(s, off, 64);
    if (lane == 0) thr_s = 0.05f * fmaxf(s / (float)n, 1e-6f);
  }
  __syncthreads();
  const float thr = thr_s;

  const int n4 = n >> 2;
  for (int i = blockIdx.x * 256 + threadIdx.x; i < n4; i += gridDim.x * 256) {
    float4 v = *(const float4*)(w + (long)i * 4);
    ushort4 o;
    o.x = v.x > thr ? 0x3C00 : (v.x < -thr ? 0xBC00 : 0);
    o.y = v.y > thr ? 0x3C00 : (v.y < -thr ? 0xBC00 : 0);
    o.z = v.z > thr ? 0x3C00 : (v.z < -thr ? 0xBC00 : 0);
    o.w = v.w > thr ? 0x3C00 : (v.w < -thr ? 0xBC00 : 0);
    *(ushort4*)(t + (long)i * 4) = o;
  }
}

// ---------------- qkv GEMM: 128x128 tile, 2 waves of 64x128 -----------------
// 768 blocks = exactly 3/CU (round-14's 384-block grid left 25% of CU-time
// idle).  Wave tile 64x128 keeps 0.25 ds_reads/MFMA (round-12's win).
// LDS 48KB (A-hi 8K | A-lo 8K | B 8K, double-buffered).  Same proven parts:
// row-XOR chunk swizzle, coalesced global_load_lds source, 2-buffer
// vmcnt(0)+barrier loop, XCD chunking.  Epilogue by output column.
__global__ __launch_bounds__(128, 2)
void gemm_qkv(const f16* __restrict__ Ah, const f16* __restrict__ Al,
              const f16* __restrict__ Bw,
              f16* __restrict__ O1, f16* __restrict__ O2,
              f16* __restrict__ K1, f16* __restrict__ K2,
              f16* __restrict__ OV) {
  constexpr int BUFSZ = 24576;   // bytes: A-hi 8K | A-lo 8K | B 8K
  __shared__ __attribute__((aligned(16))) char smem[2 * BUFSZ];

  // XCD-chunked bijective swizzle over 768 blocks (768 % 8 == 0)
  const int id2 = (blockIdx.x & 7) * 96 + (blockIdx.x >> 3);
  const int bx  = id2 % 24;            // N = 3072 / 128
  const int by  = id2 / 24;
  const int brow = by * 128;
  const int bcol = bx * 128;

  const int tid  = threadIdx.x;
  const int lane = tid & 63;
  const int wv   = tid >> 6;           // 0 or 1
  const int wr   = wv * 64;            // wave rows
  const int fr   = lane & 15;
  const int fq   = lane >> 4;

  const bool lo_on = bcol < 2560;      // V region doesn't need the x_lo pass

  // staging: lane -> row (lane>>2) of a 16-row group, chunk pre-permuted
  // (XOR swizzle); 4 lanes cover one row's contiguous 64B (coalesced).
  const int rl  = lane >> 2;
  const int scg = ((lane & 3) ^ ((lane >> 3) & 3)) * 8;  // f16 offset in row
  const f16* gA0 = Ah + (long)(brow + wv * 64 + rl) * DIM_ + scg;
  const f16* gL0 = Al + (long)(brow + wv * 64 + rl) * DIM_ + scg;
  const f16* gB0 = Bw + (long)(bcol + wv * 64 + rl) * DIM_ + scg;
  const int wvb = __builtin_amdgcn_readfirstlane(wv * 2048);  // f16 units

  auto STAGE = [&](int kt, int buf) {
    const int k0 = kt * 32;
    char* base = smem + buf * BUFSZ;
    f16* lA = (f16*)base + wvb;                  // A-hi region [0,8K)
    f16* lL = (f16*)(base + 8192) + wvb;         // A-lo region
    f16* lB = (f16*)(base + 16384) + wvb;        // B region
    #pragma unroll
    for (int g = 0; g < 4; ++g) {
      gload16(gA0 + k0 + g * 16 * DIM_, lA + g * 512);
      gload16(gB0 + k0 + g * 16 * DIM_, lB + g * 512);
    }
    if (lo_on) {
      #pragma unroll
      for (int g = 0; g < 4; ++g)
        gload16(gL0 + k0 + g * 16 * DIM_, lL + g * 512);
    }
  };

  // fragment read: per-thread constant chunk offset (XOR swizzle)
  const int xga = (fq ^ ((fr >> 1) & 3)) * 8;   // f16 units

  f32x4 acc[4][8] = {};
  const int nk = DIM_ / 32;   // 64: even, so last tile computes from buf1

  STAGE(0, 0);
  #pragma unroll 1
  for (int kt = 0; kt < nk; ++kt) {
    asm volatile("s_waitcnt vmcnt(0)" ::: "memory");
    __syncthreads();
    if (kt + 1 < nk) STAGE(kt + 1, (kt + 1) & 1);   // prefetch under compute

    const char* base = smem + (kt & 1) * BUFSZ;
    const f16* cAh = (const f16*)base;
    const f16* cAl = (const f16*)(base + 8192);
    const f16* cB  = (const f16*)(base + 16384);

    f16x8 bfr[8];
    #pragma unroll
    for (int ni = 0; ni < 8; ++ni)
      bfr[ni] = *(const f16x8*)(cB + (ni * 16 + fr) * 32 + xga);
    #pragma unroll
    for (int mi = 0; mi < 4; ++mi) {
      const int aoff = (wr + mi * 16 + fr) * 32 + xga;
      f16x8 ah = *(const f16x8*)(cAh + aoff);
      #pragma unroll
      for (int ni = 0; ni < 8; ++ni)
        acc[mi][ni] = mfma16(ah, bfr[ni], acc[mi][ni]);
      if (lo_on) {
        f16x8 al = *(const f16x8*)(cAl + aoff);
        #pragma unroll
        for (int ni = 0; ni < 8; ++ni)
          acc[mi][ni] = mfma16(al, bfr[ni], acc[mi][ni]);
      }
    }
  }

  const int colbase = bcol;        // multiple of 128; regions 128-aligned
  if (colbase < 2048) {            // q -> hi/lo, stride DIM_
    #pragma unroll
    for (int mi = 0; mi < 4; ++mi)
      #pragma unroll
      for (int ni = 0; ni < 8; ++ni)
        #pragma unroll
        for (int r = 0; r < 4; ++r) {
          long idx = (long)(brow + wr + mi * 16 + fq * 4 + r) * DIM_
                   + colbase + ni * 16 + fr;
          float v = acc[mi][ni][r];
          f16 hv = (f16)v;
          O1[idx] = hv;
          O2[idx] = (f16)(v - (float)hv);
        }
  } else if (colbase < 2560) {     // k -> hi/lo, stride KVW_
    #pragma unroll
    for (int mi = 0; mi < 4; ++mi)
      #pragma unroll
      for (int ni = 0; ni < 8; ++ni)
        #pragma unroll
        for (int r = 0; r < 4; ++r) {
          long idx = (long)(brow + wr + mi * 16 + fq * 4 + r) * KVW_
                   + (colbase - 2048) + ni * 16 + fr;
          float v = acc[mi][ni][r];
          f16 hv = (f16)v;
          K1[idx] = hv;
          K2[idx] = (f16)(v - (float)hv);
        }
  } else {                         // v -> transpose to [b][kvh][d][s]
    // scratch aliases buf0: last tile (kt=63, odd) computed from buf1, and
    // the final top-of-loop vmcnt(0)+barrier drained all staging. Wave-local.
    f16* st = (f16*)smem + wv * 32 * 72;   // per-wave [32 d][64 s] pad 72
    const int bb = brow >> 11;             // batch
    const int s0 = (brow & (SEQ_ - 1)) + wr;
    #pragma unroll
    for (int nh = 0; nh < 4; ++nh) {       // four 32-wide d-chunks (2 kv-heads)
      const int khh = ((colbase - 2560) >> 6) + (nh >> 1);
      const int db  = (nh & 1) * 32;
      #pragma unroll
      for (int nj = 0; nj < 2; ++nj) {
        const int ni = nh * 2 + nj;
        #pragma unroll
        for (int mi = 0; mi < 4; ++mi)
          #pragma unroll
          for (int r = 0; r < 4; ++r)
            st[(nj * 16 + fr) * 72 + mi * 16 + fq * 4 + r] = (f16)acc[mi][ni][r];
      }
      // wave-local write->read; compiler inserts lgkmcnt waits
      #pragma unroll
      for (int i = 0; i < 4; ++i) {
        int dl = i * 8 + (lane >> 3);
        f16x8 v = *(const f16x8*)(st + dl * 72 + (lane & 7) * 8);
        *(f16x8*)(OV + ((long)(bb * 8 + khh) * 64 + db + dl) * SEQ_
                  + s0 + (lane & 7) * 8) = v;
      }
    }
  }
}

// ---------------- o-proj GEMM (proven 128x128 non-split) --------------------
__global__ __launch_bounds__(256)
void gemm_o(const f16* __restrict__ A, const f16* __restrict__ Bw,
            float* __restrict__ C) {
  constexpr int BUFSZ = 16384;   // [A 8K | B 8K]
  __shared__ __attribute__((aligned(16))) char smem[2 * BUFSZ];

  const int cpx = gridDim.x >> 3;
  const int id2 = (blockIdx.x & 7) * cpx + (blockIdx.x >> 3);
  const int nbx = DIM_ >> 7;
  const int bx  = id2 % nbx;
  const int by  = id2 / nbx;
  const int brow = by * 128;
  const int bcol = bx * 128;

  const int tid  = threadIdx.x;
  const int lane = tid & 63;
  const int wv   = tid >> 6;
  const int wr   = (wv >> 1) * 64;
  const int wc   = (wv & 1) * 64;
  const int fr   = lane & 15;
  const int fq   = lane >> 4;

  const int srw = wv * 32 + (lane >> 2);
  const int scg = ((lane & 3) ^ ((lane >> 3) & 3)) * 8;
  const f16* gA0 = A + (long)(brow + srw) * DIM_ + scg;
  const f16* gA1 = gA0 + 16 * (long)DIM_;
  const f16* gB0 = Bw + (long)(bcol + srw) * DIM_ + scg;
  const f16* gB1 = gB0 + 16 * (long)DIM_;
  const int wvb = __builtin_amdgcn_readfirstlane(wv * 1024);

  auto STAGE = [&](int kt, int buf) {
    const int k0 = kt * 32;
    char* base = smem + buf * BUFSZ;
    f16* lA = (f16*)base + wvb;
    f16* lB = (f16*)(base + 8192) + wvb;
    gload16(gA0 + k0, lA);
    gload16(gA1 + k0, lA + 512);
    gload16(gB0 + k0, lB);
    gload16(gB1 + k0, lB + 512);
  };

  const int xga = (fq ^ ((fr >> 1) & 3)) * 8;

  f32x4 acc[4][4] = {};
  const int nk = DIM_ >> 5;

  STAGE(0, 0);
  #pragma unroll 1
  for (int kt = 0; kt < nk; ++kt) {
    asm volatile("s_waitcnt vmcnt(0)" ::: "memory");
    __syncthreads();
    if (kt + 1 < nk) STAGE(kt + 1, (kt + 1) & 1);

    const char* base = smem + (kt & 1) * BUFSZ;
    const f16* cA = (const f16*)base;
    const f16* cB = (const f16*)(base + 8192);

    f16x8 bfr[4];
    #pragma unroll
    for (int ni = 0; ni < 4; ++ni)
      bfr[ni] = *(const f16x8*)(cB + (wc + ni * 16 + fr) * 32 + xga);
    #pragma unroll
    for (int mi = 0; mi < 4; ++mi) {
      f16x8 ah = *(const f16x8*)(cA + (wr + mi * 16 + fr) * 32 + xga);
      #pragma unroll
      for (int ni = 0; ni < 4; ++ni)
        acc[mi][ni] = mfma16(ah, bfr[ni], acc[mi][ni]);
    }
  }

  #pragma unroll
  for (int mi = 0; mi < 4; ++mi)
    #pragma unroll
    for (int ni = 0; ni < 4; ++ni)
      #pragma unroll
      for (int r = 0; r < 4; ++r)
        C[(long)(brow + wr + mi * 16 + fq * 4 + r) * DIM_ + (bcol + wc + ni * 16 + fr)]
            = acc[mi][ni][r];
}

// ---------------- flash attention v6: 1024 blocks, 3 blocks/CU --------------
// (round-14 proven: grid supplies 3 blocks/CU; LPT big-first order; K single-
// buffered, V double-buffered; two barriers per iter.)
__global__ __launch_bounds__(256, 3)
void attn_kernel(const f16* __restrict__ qhi, const f16* __restrict__ qlo,
                 const f16* __restrict__ khi, const f16* __restrict__ klo,
                 const f16* __restrict__ vt,  f16* __restrict__ AO) {
  // 1024 blocks: id2 = xcd*128 + local; local -> (tile big-first, combo)
  const int id2   = (blockIdx.x & 7) * 128 + (blockIdx.x >> 3);
  const int local = id2 & 127;
  const int t     = 63 - (local >> 1);         // 63..0: big tiles first
  const int cmb   = (id2 >> 7) * 2 + (local & 1);
  const int kh    = cmb & 7;
  const int b     = cmb >> 3;
  const int tid  = threadIdx.x;
  const int lane = tid & 63;
  const int w    = tid >> 6;
  const int fr   = lane & 15;
  const int fq   = lane >> 4;
  const int h    = kh * 4 + w;           // each wave owns one GQA head
  const int xr   = (fr & 7) << 4;        // XOR swizzle for 16B chunks

  __shared__ __attribute__((aligned(16))) char sKh[64 * 128];      // single buf
  __shared__ __attribute__((aligned(16))) char sKl[64 * 128];      // single buf
  __shared__ __attribute__((aligned(16))) char sVt[2][64 * 128];   // double buf
  __shared__ __attribute__((aligned(16))) char sP [4][2][16 * 128];

  const int srow = w * 16 + (lane >> 3);
  const int scol = ((lane & 7) ^ (lane >> 3)) * 8;   // (srow&7)==(lane>>3)
  const f16* gK0 = khi + ((long)(b * SEQ_) + srow) * KVW_ + kh * HD_ + scol;
  const f16* gL0 = klo + ((long)(b * SEQ_) + srow) * KVW_ + kh * HD_ + scol;
  const f16* gV0 = vt + ((long)(b * 8 + kh) * HD_ + srow) * SEQ_ + scol;
  const int ldso = __builtin_amdgcn_readfirstlane(w * 2048);  // wave-uniform

  auto STAGE_K = [&](int kb) {
    const long ko = (long)kb * 64 * KVW_;
    gload16(gK0 + ko,            sKh + ldso);
    gload16(gK0 + ko + 8 * KVW_, sKh + ldso + 1024);
    gload16(gL0 + ko,            sKl + ldso);
    gload16(gL0 + ko + 8 * KVW_, sKl + ldso + 1024);
  };
  auto STAGE_V = [&](int kb, int buf) {
    const long vo = (long)kb * 64;
    gload16(gV0 + vo,            (char*)sVt[buf] + ldso);
    gload16(gV0 + vo + 8 * SEQ_, (char*)sVt[buf] + ldso + 1024);
  };

  char* pw0 = sP[w][0];
  char* pw1 = sP[w][1];
  const float ce = 0.125f * 1.44269504f;  // exp2 scale (1/sqrt(64) folded)

  const int nkv   = (t >> 1) + 1;
  const int qrow0 = t * 32;

  f16x8 qh[2][2], ql[2][2];
  #pragma unroll
  for (int st = 0; st < 2; ++st)
    #pragma unroll
    for (int ks = 0; ks < 2; ++ks) {
      const long qoff = (long)(b * SEQ_ + qrow0 + st * 16 + fr) * DIM_
                      + h * HD_ + ks * 32 + fq * 8;
      qh[st][ks] = *(const f16x8*)(qhi + qoff);
      ql[st][ks] = *(const f16x8*)(qlo + qoff);
    }

  STAGE_K(0);               // prologue: K[0], V[0] (buffers fresh, no barrier)
  STAGE_V(0, 0);

  float m0 = -1e30f, m1 = -1e30f, l0 = 0.f, l1 = 0.f;
  f32x4 o0[4] = {}, o1[4] = {};

  #pragma unroll 1
  for (int kb = 0; kb < nkv; ++kb) {
    // barrier1: every wave's K[kb]+V[kb] portions landed AND every wave
    // finished PV[kb-1] (so V buf (kb+1)&1 is overwritable).
    asm volatile("s_waitcnt vmcnt(0)" ::: "memory");
    __syncthreads();
    if (kb + 1 < nkv) STAGE_V(kb + 1, (kb + 1) & 1);
    const char* bV = sVt[kb & 1];

    // S^T = K Q^T (hi/lo 3-pass); lane holds q-row fr, k = ni*16+fq*4+r
    f32x4 s0[4] = {}, s1[4] = {};
    __builtin_amdgcn_s_setprio(1);
    #pragma unroll
    for (int ks = 0; ks < 2; ++ks)
      #pragma unroll
      for (int ni = 0; ni < 4; ++ni) {
        const int rb = (ni * 16 + fr) * 128 + ((ks * 64 + fq * 16) ^ xr);
        f16x8 ah = *(const f16x8*)(sKh + rb);
        f16x8 af = *(const f16x8*)(sKl + rb);
        s0[ni] = mfma16(ah, qh[0][ks], s0[ni]);
        s0[ni] = mfma16(ah, ql[0][ks], s0[ni]);
        s0[ni] = mfma16(af, qh[0][ks], s0[ni]);
        s1[ni] = mfma16(ah, qh[1][ks], s1[ni]);
        s1[ni] = mfma16(ah, ql[1][ks], s1[ni]);
        s1[ni] = mfma16(af, qh[1][ks], s1[ni]);
      }
    __builtin_amdgcn_s_setprio(0);

    // barrier2: all waves done reading K[kb] -> safe to overwrite K buffer
    __syncthreads();
    if (kb + 1 < nkv) STAGE_K(kb + 1);   // flies under softmax+PV

    if (kb == nkv - 1) {                 // causal mask on diagonal tile
      #pragma unroll
      for (int ni = 0; ni < 4; ++ni)
        #pragma unroll
        for (int r = 0; r < 4; ++r) {
          const int kk = ni * 16 + fq * 4 + r;
          if (kk > (t & 1) * 32 + fr)      s0[ni][r] = -1e30f;
          if (kk > (t & 1) * 32 + 16 + fr) s1[ni][r] = -1e30f;
        }
    }

    // online softmax per subtile (defer-max: rescale only on >64 raw growth)
    #pragma unroll
    for (int st = 0; st < 2; ++st) {
      f32x4* s = st ? s1 : s0;
      float& m = st ? m1 : m0;
      float& l = st ? l1 : l0;
      f32x4* o = st ? o1 : o0;
      char* pw = st ? pw1 : pw0;

      float ma = fmaxf(fmaxf(s[0][0], s[0][1]), fmaxf(s[0][2], s[0][3]));
      float mb2 = fmaxf(fmaxf(s[1][0], s[1][1]), fmaxf(s[1][2], s[1][3]));
      float mc = fmaxf(fmaxf(s[2][0], s[2][1]), fmaxf(s[2][2], s[2][3]));
      float md = fmaxf(fmaxf(s[3][0], s[3][1]), fmaxf(s[3][2], s[3][3]));
      float mb = fmaxf(fmaxf(ma, mb2), fmaxf(mc, md));
      mb = fmaxf(mb, __shfl_xor(mb, 16, 64));
      mb = fmaxf(mb, __shfl_xor(mb, 32, 64));

      const float mo = m;
      const bool trig = mb > mo + 64.f;
      const float mn = trig ? mb : mo;
      m = mn;
      const float al = exp2f((mo - mn) * ce);  // ==1 when !trig
      const float tt = mn * ce;

      float rs = 0.f;
      #pragma unroll
      for (int ni = 0; ni < 4; ++ni) {
        #pragma unroll
        for (int r = 0; r < 4; ++r) {
          float pv = exp2f(fmaf(s[ni][r], ce, -tt));
          s[ni][r] = pv;
          rs += pv;
        }
        *(unsigned long long*)(pw + ((fr * 128 + ni * 32 + fq * 8) ^ xr)) =
            pk4(s[ni][0], s[ni][1], s[ni][2], s[ni][3]);
      }
      rs += __shfl_xor(rs, 16, 64);
      rs += __shfl_xor(rs, 32, 64);
      l = l * al + rs;

      if (__any(trig)) {                 // o rows live at fq*4+r
        #pragma unroll
        for (int r = 0; r < 4; ++r) {
          float alr = __shfl(al, ((lane >> 4) << 2) + r, 64);
          o[0][r] *= alr; o[1][r] *= alr; o[2][r] *= alr; o[3][r] *= alr;
        }
      }
    }

    // O += P V (vt fragments shared across both subtiles)
    __builtin_amdgcn_s_setprio(1);
    #pragma unroll
    for (int ks = 0; ks < 2; ++ks) {
      const int pb = (fr * 128 + ks * 64 + fq * 16) ^ xr;
      f16x8 pa0 = *(const f16x8*)(pw0 + pb);
      f16x8 pa1 = *(const f16x8*)(pw1 + pb);
      #pragma unroll
      for (int di = 0; di < 4; ++di) {
        f16x8 vf = *(const f16x8*)(bV + (di * 16 + fr) * 128
                                   + ((ks * 64 + fq * 16) ^ xr));
        o0[di] = mfma16(pa0, vf, o0[di]);
        o1[di] = mfma16(pa1, vf, o1[di]);
      }
    }
    __builtin_amdgcn_s_setprio(0);
  }

  // epilogue: divide by row sums (broadcast l to rows fq*4+r) and store
  #pragma unroll
  for (int st = 0; st < 2; ++st) {
    const f32x4* o = st ? o1 : o0;
    const float l = st ? l1 : l0;
    float linv[4];
    #pragma unroll
    for (int r = 0; r < 4; ++r)
      linv[r] = 1.f / __shfl(l, ((lane >> 4) << 2) + r, 64);
    #pragma unroll
    for (int di = 0; di < 4; ++di)
      #pragma unroll
      for (int r = 0; r < 4; ++r)
        AO[(long)(b * SEQ_ + qrow0 + st * 16 + fq * 4 + r) * DIM_
           + h * HD_ + di * 16 + fr] = (f16)(o[di][r] * linv[r]);
  }
}

// ---------------- launch ----------------
extern "C" void kernel_launch(void* const* d_in, const int* in_sizes, int n_in,
                              void* d_out, int out_size, void* d_ws, size_t ws_size,
                              hipStream_t stream) {
  const float* x  = (const float*)d_in[0];
  const float* wq = (const float*)d_in[1];
  const float* wk = (const float*)d_in[2];
  const float* wv = (const float*)d_in[3];
  const float* wo = (const float*)d_in[4];
  char* ws = (char*)d_ws;

  size_t off = 0;
  float* parts = (float*)ws;                off = 4096;
  f16* x_hi  = (f16*)(ws + off);            off += (size_t)MROWS_ * DIM_ * 2;
  f16* x_lo  = (f16*)(ws + off);            off += (size_t)MROWS_ * DIM_ * 2;
  f16* wq_t  = (f16*)(ws + off);            off += (size_t)DIM_ * DIM_ * 2;
  f16* wkv_t = (f16*)(ws + off);            off += (size_t)1024 * DIM_ * 2;  // contiguous after wq_t
  f16* wo_t  = (f16*)(ws + off);            off += (size_t)DIM_ * DIM_ * 2;
  f16* qhi   = (f16*)(ws + off);            off += (size_t)MROWS_ * DIM_ * 2;
  f16* qlo   = (f16*)(ws + off);            off += (size_t)MROWS_ * DIM_ * 2;
  f16* khi   = (f16*)(ws + off);            off += (size_t)MROWS_ * KVW_ * 2;
  f16* klo   = (f16*)(ws + off);            off += (size_t)MROWS_ * KVW_ * 2;
  f16* vtb   = (f16*)(ws + off);            off += (size_t)BATCH_ * 8 * 64 * SEQ_ * 2;
  f16* ao    = (f16*)(ws + off);            off += (size_t)MROWS_ * DIM_ * 2;

  // prep: |w| partials + x hi/lo split in one launch; ternarize reduces the
  // partials inline (deterministic fixed-order tree, no atomics anywhere)
  prep1<<<dim3(192, 6), dim3(256), 0, stream>>>(x, wq, wk, wv, wo,
                                                parts, x_hi, x_lo);
  ternarize4<<<dim3(192, 4), dim3(256), 0, stream>>>(
      wq, wk, wv, wo,
      (unsigned short*)wq_t, (unsigned short*)wkv_t,
      (unsigned short*)(wkv_t + (size_t)KVW_ * DIM_), (unsigned short*)wo_t,
      parts);

  // fused q+k+v projection: B = [wq_t ; wk_t ; wv_t] = 3072 rows (contiguous)
  gemm_qkv<<<dim3(768), dim3(128), 0, stream>>>(
      x_hi, x_lo, wq_t, qhi, qlo, khi, klo, vtb);

  attn_kernel<<<dim3(1024), dim3(256), 0, stream>>>(
      qhi, qlo, khi, klo, vtb, ao);

  gemm_o<<<dim3((DIM_ / 128) * (MROWS_ / 128)), dim3(256), 0, stream>>>(
      ao, wo_t, (float*)d_out);
}

// Round 16
// 271.713 us; speedup vs baseline: 1.0193x; 1.0193x over previous
//
#include <hip/hip_runtime.h>

typedef _Float16 f16;
typedef f16  f16x8 __attribute__((ext_vector_type(8)));
typedef f16  f16x4 __attribute__((ext_vector_type(4)));
typedef float f32x4 __attribute__((ext_vector_type(4)));

#define DIM_   2048
#define SEQ_   2048
#define BATCH_ 2
#define MROWS_ (BATCH_*SEQ_)   // 4096
#define HD_    64
#define KVW_   512             // k (or v) projection width

__device__ __forceinline__ f32x4 mfma16(f16x8 a, f16x8 b, f32x4 c) {
  return __builtin_amdgcn_mfma_f32_16x16x32_f16(a, b, c, 0, 0, 0);
}

// async global->LDS, 16B per lane; LDS dest is wave-uniform base + lane*16
typedef const __attribute__((address_space(1))) void gas_void;
typedef __attribute__((address_space(3))) void las_void;
__device__ __forceinline__ void gload16(const void* g, void* l) {
  __builtin_amdgcn_global_load_lds((gas_void*)g, (las_void*)l, 16, 0, 0);
}

// pack 4 f32 -> 4 f16 (RTZ) as one 8B word for ds_write_b64
__device__ __forceinline__ unsigned long long pk4(float a, float b, float c, float d) {
  union { _Float16 h[4]; unsigned long long u; } z;
  auto p0 = __builtin_amdgcn_cvt_pkrtz(a, b);
  auto p1 = __builtin_amdgcn_cvt_pkrtz(c, d);
  z.h[0] = p0[0]; z.h[1] = p0[1]; z.h[2] = p1[0]; z.h[3] = p1[1];
  return z.u;
}

// ---------------- prep1: |w| per-block partials (y=0..3) + x hi/lo split
// (y=4..5).  NO atomics: fixed orders everywhere -> replay-deterministic.
__global__ __launch_bounds__(256)
void prep1(const float* __restrict__ x,
           const float* __restrict__ w0, const float* __restrict__ w1,
           const float* __restrict__ w2, const float* __restrict__ w3,
           float* __restrict__ parts, f16* __restrict__ hi, f16* __restrict__ lo) {
  const int id = blockIdx.y;
  if (id < 4) {
    const float* w = id == 0 ? w0 : id == 1 ? w1 : id == 2 ? w2 : w3;
    const int n4 = (id == 1 || id == 2) ? (KVW_ * DIM_ / 4) : (DIM_ * DIM_ / 4);
    float s = 0.f;
    for (int i = blockIdx.x * 256 + threadIdx.x; i < n4; i += gridDim.x * 256) {
      float4 v = *(const float4*)(w + (long)i * 4);
      s += fabsf(v.x) + fabsf(v.y) + fabsf(v.z) + fabsf(v.w);
    }
    #pragma unroll
    for (int off = 32; off > 0; off >>= 1)
      s += __shfl_down(s, off, 64);
    __shared__ float red[4];
    int lane = threadIdx.x & 63, wv = threadIdx.x >> 6;
    if (lane == 0) red[wv] = s;
    __syncthreads();
    if (threadIdx.x == 0)
      parts[id * 192 + blockIdx.x] = (red[0] + red[1]) + (red[2] + red[3]);
  } else {
    const int half = (MROWS_ * DIM_ / 4) / 2;
    const long base = (long)(id - 4) * half;
    for (int i = blockIdx.x * 256 + threadIdx.x; i < half; i += gridDim.x * 256) {
      float4 v = *(const float4*)(x + (base + i) * 4);
      f16x4 h, l;
      h[0] = (f16)v.x; l[0] = (f16)(v.x - (float)h[0]);
      h[1] = (f16)v.y; l[1] = (f16)(v.y - (float)h[1]);
      h[2] = (f16)v.z; l[2] = (f16)(v.z - (float)h[2]);
      h[3] = (f16)v.w; l[3] = (f16)(v.w - (float)h[3]);
      *(f16x4*)(hi + (base + i) * 4) = h;
      *(f16x4*)(lo + (base + i) * 4) = l;
    }
  }
}

// ---------------- ternarize (inline deterministic final reduce) -------------
__global__ __launch_bounds__(256)
void ternarize4(const float* __restrict__ w0, const float* __restrict__ w1,
                const float* __restrict__ w2, const float* __restrict__ w3,
                unsigned short* __restrict__ t0, unsigned short* __restrict__ t1,
                unsigned short* __restrict__ t2, unsigned short* __restrict__ t3,
                const float* __restrict__ parts) {
  const int id = blockIdx.y;
  const float* w = id == 0 ? w0 : id == 1 ? w1 : id == 2 ? w2 : w3;
  unsigned short* t = id == 0 ? t0 : id == 1 ? t1 : id == 2 ? t2 : t3;
  const int n = (id == 1 || id == 2) ? (KVW_ * DIM_) : (DIM_ * DIM_);

  __shared__ float thr_s;
  if (threadIdx.x < 64) {
    const int lane = threadIdx.x;
    float s = parts[id * 192 + lane] + parts[id * 192 + 64 + lane]
            + parts[id * 192 + 128 + lane];
    #pragma unroll
    for (int off = 32; off > 0; off >>= 1)
      s += __shfl_down(s, off, 64);
    if (lane == 0) thr_s = 0.05f * fmaxf(s / (float)n, 1e-6f);
  }
  __syncthreads();
  const float thr = thr_s;

  const int n4 = n >> 2;
  for (int i = blockIdx.x * 256 + threadIdx.x; i < n4; i += gridDim.x * 256) {
    float4 v = *(const float4*)(w + (long)i * 4);
    ushort4 o;
    o.x = v.x > thr ? 0x3C00 : (v.x < -thr ? 0xBC00 : 0);
    o.y = v.y > thr ? 0x3C00 : (v.y < -thr ? 0xBC00 : 0);
    o.z = v.z > thr ? 0x3C00 : (v.z < -thr ? 0xBC00 : 0);
    o.w = v.w > thr ? 0x3C00 : (v.w < -thr ? 0xBC00 : 0);
    *(ushort4*)(t + (long)i * 4) = o;
  }
}

// ---------------- qkv GEMM: 128x256 tile, 64x128 wave tiles (round-14) ------
// 4 waves (256 thr), wave tile 64x128 (acc[4][8]) -> 0.25 ds_reads/MFMA.
// 384 blocks at 1.5/CU measured FASTER than 768x2-wave at 3/CU (round-15):
// bigger B-panel reuse (FETCH 110 vs 122MB) and 2 staging gloads/wave vs 6.
// At 875 TF this sits AT the 2-barrier-structure ceiling (m97: 874-912).
__global__ __launch_bounds__(256, 2)
void gemm_qkv(const f16* __restrict__ Ah, const f16* __restrict__ Al,
              const f16* __restrict__ Bw,
              f16* __restrict__ O1, f16* __restrict__ O2,
              f16* __restrict__ K1, f16* __restrict__ K2,
              f16* __restrict__ OV) {
  constexpr int BUFSZ = 32768;   // bytes: A-hi 8K | A-lo 8K | B 16K
  __shared__ __attribute__((aligned(16))) char smem[2 * BUFSZ];

  // XCD-chunked bijective swizzle over 384 blocks (384 % 8 == 0)
  const int id2 = (blockIdx.x & 7) * 48 + (blockIdx.x >> 3);
  const int bx  = id2 % 12;
  const int by  = id2 / 12;
  const int brow = by * 128;
  const int bcol = bx * 256;

  const int tid  = threadIdx.x;
  const int lane = tid & 63;
  const int wv   = tid >> 6;
  const int wr   = (wv >> 1) * 64;    // wave rows (2 row groups)
  const int wc   = (wv & 1) * 128;    // wave cols (2 col groups of 128)
  const int fr   = lane & 15;
  const int fq   = lane >> 4;

  const bool lo_on = bcol < 2560;     // V region doesn't need the x_lo pass

  const int rl  = lane >> 2;
  const int scg = ((lane & 3) ^ ((lane >> 3) & 3)) * 8;  // f16 offset in row
  const f16* gA0 = Ah + (long)(brow + wv * 32 + rl) * DIM_ + scg;
  const f16* gL0 = Al + (long)(brow + wv * 32 + rl) * DIM_ + scg;
  const f16* gB0 = Bw + (long)(bcol + wv * 64 + rl) * DIM_ + scg;
  const int wvbA = __builtin_amdgcn_readfirstlane(wv * 1024);  // f16 units
  const int wvbB = __builtin_amdgcn_readfirstlane(wv * 2048);

  auto STAGE = [&](int kt, int buf) {
    const int k0 = kt * 32;
    char* base = smem + buf * BUFSZ;
    f16* lA = (f16*)base + wvbA;                 // A-hi region
    f16* lL = (f16*)(base + 8192) + wvbA;        // A-lo region
    f16* lB = (f16*)(base + 16384) + wvbB;       // B region
    gload16(gA0 + k0, lA);
    gload16(gA0 + k0 + 16 * DIM_, lA + 512);
    gload16(gB0 + k0, lB);
    gload16(gB0 + k0 + 16 * DIM_, lB + 512);
    gload16(gB0 + k0 + 32 * DIM_, lB + 1024);
    gload16(gB0 + k0 + 48 * DIM_, lB + 1536);
    if (lo_on) {
      gload16(gL0 + k0, lL);
      gload16(gL0 + k0 + 16 * DIM_, lL + 512);
    }
  };

  const int xga = (fq ^ ((fr >> 1) & 3)) * 8;   // f16 units

  f32x4 acc[4][8] = {};
  const int nk = DIM_ / 32;   // 64: even, so last tile computes from buf1

  STAGE(0, 0);
  #pragma unroll 1
  for (int kt = 0; kt < nk; ++kt) {
    asm volatile("s_waitcnt vmcnt(0)" ::: "memory");
    __syncthreads();
    if (kt + 1 < nk) STAGE(kt + 1, (kt + 1) & 1);   // prefetch under compute

    const char* base = smem + (kt & 1) * BUFSZ;
    const f16* cAh = (const f16*)base;
    const f16* cAl = (const f16*)(base + 8192);
    const f16* cB  = (const f16*)(base + 16384);

    f16x8 bfr[8];
    #pragma unroll
    for (int ni = 0; ni < 8; ++ni)
      bfr[ni] = *(const f16x8*)(cB + (wc + ni * 16 + fr) * 32 + xga);
    #pragma unroll
    for (int mi = 0; mi < 4; ++mi) {
      const int aoff = (wr + mi * 16 + fr) * 32 + xga;
      f16x8 ah = *(const f16x8*)(cAh + aoff);
      #pragma unroll
      for (int ni = 0; ni < 8; ++ni)
        acc[mi][ni] = mfma16(ah, bfr[ni], acc[mi][ni]);
      if (lo_on) {
        f16x8 al = *(const f16x8*)(cAl + aoff);
        #pragma unroll
        for (int ni = 0; ni < 8; ++ni)
          acc[mi][ni] = mfma16(al, bfr[ni], acc[mi][ni]);
      }
    }
  }

  const int colbase = bcol + wc;   // multiple of 128; regions 128-aligned
  if (colbase < 2048) {            // q -> hi/lo, stride DIM_
    #pragma unroll
    for (int mi = 0; mi < 4; ++mi)
      #pragma unroll
      for (int ni = 0; ni < 8; ++ni)
        #pragma unroll
        for (int r = 0; r < 4; ++r) {
          long idx = (long)(brow + wr + mi * 16 + fq * 4 + r) * DIM_
                   + colbase + ni * 16 + fr;
          float v = acc[mi][ni][r];
          f16 hv = (f16)v;
          O1[idx] = hv;
          O2[idx] = (f16)(v - (float)hv);
        }
  } else if (colbase < 2560) {     // k -> hi/lo, stride KVW_
    #pragma unroll
    for (int mi = 0; mi < 4; ++mi)
      #pragma unroll
      for (int ni = 0; ni < 8; ++ni)
        #pragma unroll
        for (int r = 0; r < 4; ++r) {
          long idx = (long)(brow + wr + mi * 16 + fq * 4 + r) * KVW_
                   + (colbase - 2048) + ni * 16 + fr;
          float v = acc[mi][ni][r];
          f16 hv = (f16)v;
          K1[idx] = hv;
          K2[idx] = (f16)(v - (float)hv);
        }
  } else {                         // v -> transpose to [b][kvh][d][s]
    f16* st = (f16*)smem + wv * 32 * 72;   // per-wave [32 d][64 s] pad 72
    const int bb = brow >> 11;             // batch
    const int s0 = (brow & (SEQ_ - 1)) + wr;
    #pragma unroll
    for (int nh = 0; nh < 4; ++nh) {       // four 32-wide d-chunks (2 kv-heads)
      const int khh = ((colbase - 2560) >> 6) + (nh >> 1);
      const int db  = (nh & 1) * 32;
      #pragma unroll
      for (int nj = 0; nj < 2; ++nj) {
        const int ni = nh * 2 + nj;
        #pragma unroll
        for (int mi = 0; mi < 4; ++mi)
          #pragma unroll
          for (int r = 0; r < 4; ++r)
            st[(nj * 16 + fr) * 72 + mi * 16 + fq * 4 + r] = (f16)acc[mi][ni][r];
      }
      #pragma unroll
      for (int i = 0; i < 4; ++i) {
        int dl = i * 8 + (lane >> 3);
        f16x8 v = *(const f16x8*)(st + dl * 72 + (lane & 7) * 8);
        *(f16x8*)(OV + ((long)(bb * 8 + khh) * 64 + db + dl) * SEQ_
                  + s0 + (lane & 7) * 8) = v;
      }
    }
  }
}

// ---------------- o-proj GEMM (proven 128x128 non-split) --------------------
__global__ __launch_bounds__(256)
void gemm_o(const f16* __restrict__ A, const f16* __restrict__ Bw,
            float* __restrict__ C) {
  constexpr int BUFSZ = 16384;   // [A 8K | B 8K]
  __shared__ __attribute__((aligned(16))) char smem[2 * BUFSZ];

  const int cpx = gridDim.x >> 3;
  const int id2 = (blockIdx.x & 7) * cpx + (blockIdx.x >> 3);
  const int nbx = DIM_ >> 7;
  const int bx  = id2 % nbx;
  const int by  = id2 / nbx;
  const int brow = by * 128;
  const int bcol = bx * 128;

  const int tid  = threadIdx.x;
  const int lane = tid & 63;
  const int wv   = tid >> 6;
  const int wr   = (wv >> 1) * 64;
  const int wc   = (wv & 1) * 64;
  const int fr   = lane & 15;
  const int fq   = lane >> 4;

  const int srw = wv * 32 + (lane >> 2);
  const int scg = ((lane & 3) ^ ((lane >> 3) & 3)) * 8;
  const f16* gA0 = A + (long)(brow + srw) * DIM_ + scg;
  const f16* gA1 = gA0 + 16 * (long)DIM_;
  const f16* gB0 = Bw + (long)(bcol + srw) * DIM_ + scg;
  const f16* gB1 = gB0 + 16 * (long)DIM_;
  const int wvb = __builtin_amdgcn_readfirstlane(wv * 1024);

  auto STAGE = [&](int kt, int buf) {
    const int k0 = kt * 32;
    char* base = smem + buf * BUFSZ;
    f16* lA = (f16*)base + wvb;
    f16* lB = (f16*)(base + 8192) + wvb;
    gload16(gA0 + k0, lA);
    gload16(gA1 + k0, lA + 512);
    gload16(gB0 + k0, lB);
    gload16(gB1 + k0, lB + 512);
  };

  const int xga = (fq ^ ((fr >> 1) & 3)) * 8;

  f32x4 acc[4][4] = {};
  const int nk = DIM_ >> 5;

  STAGE(0, 0);
  #pragma unroll 1
  for (int kt = 0; kt < nk; ++kt) {
    asm volatile("s_waitcnt vmcnt(0)" ::: "memory");
    __syncthreads();
    if (kt + 1 < nk) STAGE(kt + 1, (kt + 1) & 1);

    const char* base = smem + (kt & 1) * BUFSZ;
    const f16* cA = (const f16*)base;
    const f16* cB = (const f16*)(base + 8192);

    f16x8 bfr[4];
    #pragma unroll
    for (int ni = 0; ni < 4; ++ni)
      bfr[ni] = *(const f16x8*)(cB + (wc + ni * 16 + fr) * 32 + xga);
    #pragma unroll
    for (int mi = 0; mi < 4; ++mi) {
      f16x8 ah = *(const f16x8*)(cA + (wr + mi * 16 + fr) * 32 + xga);
      #pragma unroll
      for (int ni = 0; ni < 4; ++ni)
        acc[mi][ni] = mfma16(ah, bfr[ni], acc[mi][ni]);
    }
  }

  #pragma unroll
  for (int mi = 0; mi < 4; ++mi)
    #pragma unroll
    for (int ni = 0; ni < 4; ++ni)
      #pragma unroll
      for (int r = 0; r < 4; ++r)
        C[(long)(brow + wr + mi * 16 + fq * 4 + r) * DIM_ + (bcol + wc + ni * 16 + fr)]
            = acc[mi][ni][r];
}

// ---------------- flash attention v6: 1024 blocks, 3 blocks/CU --------------
// (round-14 proven: grid supplies 3 blocks/CU; LPT big-first order; K single-
// buffered, V double-buffered; two barriers per iter.)
__global__ __launch_bounds__(256, 3)
void attn_kernel(const f16* __restrict__ qhi, const f16* __restrict__ qlo,
                 const f16* __restrict__ khi, const f16* __restrict__ klo,
                 const f16* __restrict__ vt,  f16* __restrict__ AO) {
  // 1024 blocks: id2 = xcd*128 + local; local -> (tile big-first, combo)
  const int id2   = (blockIdx.x & 7) * 128 + (blockIdx.x >> 3);
  const int local = id2 & 127;
  const int t     = 63 - (local >> 1);         // 63..0: big tiles first
  const int cmb   = (id2 >> 7) * 2 + (local & 1);
  const int kh    = cmb & 7;
  const int b     = cmb >> 3;
  const int tid  = threadIdx.x;
  const int lane = tid & 63;
  const int w    = tid >> 6;
  const int fr   = lane & 15;
  const int fq   = lane >> 4;
  const int h    = kh * 4 + w;           // each wave owns one GQA head
  const int xr   = (fr & 7) << 4;        // XOR swizzle for 16B chunks

  __shared__ __attribute__((aligned(16))) char sKh[64 * 128];      // single buf
  __shared__ __attribute__((aligned(16))) char sKl[64 * 128];      // single buf
  __shared__ __attribute__((aligned(16))) char sVt[2][64 * 128];   // double buf
  __shared__ __attribute__((aligned(16))) char sP [4][2][16 * 128];

  const int srow = w * 16 + (lane >> 3);
  const int scol = ((lane & 7) ^ (lane >> 3)) * 8;   // (srow&7)==(lane>>3)
  const f16* gK0 = khi + ((long)(b * SEQ_) + srow) * KVW_ + kh * HD_ + scol;
  const f16* gL0 = klo + ((long)(b * SEQ_) + srow) * KVW_ + kh * HD_ + scol;
  const f16* gV0 = vt + ((long)(b * 8 + kh) * HD_ + srow) * SEQ_ + scol;
  const int ldso = __builtin_amdgcn_readfirstlane(w * 2048);  // wave-uniform

  auto STAGE_K = [&](int kb) {
    const long ko = (long)kb * 64 * KVW_;
    gload16(gK0 + ko,            sKh + ldso);
    gload16(gK0 + ko + 8 * KVW_, sKh + ldso + 1024);
    gload16(gL0 + ko,            sKl + ldso);
    gload16(gL0 + ko + 8 * KVW_, sKl + ldso + 1024);
  };
  auto STAGE_V = [&](int kb, int buf) {
    const long vo = (long)kb * 64;
    gload16(gV0 + vo,            (char*)sVt[buf] + ldso);
    gload16(gV0 + vo + 8 * SEQ_, (char*)sVt[buf] + ldso + 1024);
  };

  char* pw0 = sP[w][0];
  char* pw1 = sP[w][1];
  const float ce = 0.125f * 1.44269504f;  // exp2 scale (1/sqrt(64) folded)

  const int nkv   = (t >> 1) + 1;
  const int qrow0 = t * 32;

  f16x8 qh[2][2], ql[2][2];
  #pragma unroll
  for (int st = 0; st < 2; ++st)
    #pragma unroll
    for (int ks = 0; ks < 2; ++ks) {
      const long qoff = (long)(b * SEQ_ + qrow0 + st * 16 + fr) * DIM_
                      + h * HD_ + ks * 32 + fq * 8;
      qh[st][ks] = *(const f16x8*)(qhi + qoff);
      ql[st][ks] = *(const f16x8*)(qlo + qoff);
    }

  STAGE_K(0);               // prologue: K[0], V[0] (buffers fresh, no barrier)
  STAGE_V(0, 0);

  float m0 = -1e30f, m1 = -1e30f, l0 = 0.f, l1 = 0.f;
  f32x4 o0[4] = {}, o1[4] = {};

  #pragma unroll 1
  for (int kb = 0; kb < nkv; ++kb) {
    // barrier1: every wave's K[kb]+V[kb] portions landed AND every wave
    // finished PV[kb-1] (so V buf (kb+1)&1 is overwritable).
    asm volatile("s_waitcnt vmcnt(0)" ::: "memory");
    __syncthreads();
    if (kb + 1 < nkv) STAGE_V(kb + 1, (kb + 1) & 1);
    const char* bV = sVt[kb & 1];

    // S^T = K Q^T (hi/lo 3-pass); lane holds q-row fr, k = ni*16+fq*4+r
    f32x4 s0[4] = {}, s1[4] = {};
    __builtin_amdgcn_s_setprio(1);
    #pragma unroll
    for (int ks = 0; ks < 2; ++ks)
      #pragma unroll
      for (int ni = 0; ni < 4; ++ni) {
        const int rb = (ni * 16 + fr) * 128 + ((ks * 64 + fq * 16) ^ xr);
        f16x8 ah = *(const f16x8*)(sKh + rb);
        f16x8 af = *(const f16x8*)(sKl + rb);
        s0[ni] = mfma16(ah, qh[0][ks], s0[ni]);
        s0[ni] = mfma16(ah, ql[0][ks], s0[ni]);
        s0[ni] = mfma16(af, qh[0][ks], s0[ni]);
        s1[ni] = mfma16(ah, qh[1][ks], s1[ni]);
        s1[ni] = mfma16(ah, ql[1][ks], s1[ni]);
        s1[ni] = mfma16(af, qh[1][ks], s1[ni]);
      }
    __builtin_amdgcn_s_setprio(0);

    // barrier2: all waves done reading K[kb] -> safe to overwrite K buffer
    __syncthreads();
    if (kb + 1 < nkv) STAGE_K(kb + 1);   // flies under softmax+PV

    if (kb == nkv - 1) {                 // causal mask on diagonal tile
      #pragma unroll
      for (int ni = 0; ni < 4; ++ni)
        #pragma unroll
        for (int r = 0; r < 4; ++r) {
          const int kk = ni * 16 + fq * 4 + r;
          if (kk > (t & 1) * 32 + fr)      s0[ni][r] = -1e30f;
          if (kk > (t & 1) * 32 + 16 + fr) s1[ni][r] = -1e30f;
        }
    }

    // online softmax per subtile (defer-max: rescale only on >64 raw growth)
    #pragma unroll
    for (int st = 0; st < 2; ++st) {
      f32x4* s = st ? s1 : s0;
      float& m = st ? m1 : m0;
      float& l = st ? l1 : l0;
      f32x4* o = st ? o1 : o0;
      char* pw = st ? pw1 : pw0;

      float ma = fmaxf(fmaxf(s[0][0], s[0][1]), fmaxf(s[0][2], s[0][3]));
      float mb2 = fmaxf(fmaxf(s[1][0], s[1][1]), fmaxf(s[1][2], s[1][3]));
      float mc = fmaxf(fmaxf(s[2][0], s[2][1]), fmaxf(s[2][2], s[2][3]));
      float md = fmaxf(fmaxf(s[3][0], s[3][1]), fmaxf(s[3][2], s[3][3]));
      float mb = fmaxf(fmaxf(ma, mb2), fmaxf(mc, md));
      mb = fmaxf(mb, __shfl_xor(mb, 16, 64));
      mb = fmaxf(mb, __shfl_xor(mb, 32, 64));

      const float mo = m;
      const bool trig = mb > mo + 64.f;
      const float mn = trig ? mb : mo;
      m = mn;
      const float al = exp2f((mo - mn) * ce);  // ==1 when !trig
      const float tt = mn * ce;

      float rs = 0.f;
      #pragma unroll
      for (int ni = 0; ni < 4; ++ni) {
        #pragma unroll
        for (int r = 0; r < 4; ++r) {
          float pv = exp2f(fmaf(s[ni][r], ce, -tt));
          s[ni][r] = pv;
          rs += pv;
        }
        *(unsigned long long*)(pw + ((fr * 128 + ni * 32 + fq * 8) ^ xr)) =
            pk4(s[ni][0], s[ni][1], s[ni][2], s[ni][3]);
      }
      rs += __shfl_xor(rs, 16, 64);
      rs += __shfl_xor(rs, 32, 64);
      l = l * al + rs;

      if (__any(trig)) {                 // o rows live at fq*4+r
        #pragma unroll
        for (int r = 0; r < 4; ++r) {
          float alr = __shfl(al, ((lane >> 4) << 2) + r, 64);
          o[0][r] *= alr; o[1][r] *= alr; o[2][r] *= alr; o[3][r] *= alr;
        }
      }
    }

    // O += P V (vt fragments shared across both subtiles)
    __builtin_amdgcn_s_setprio(1);
    #pragma unroll
    for (int ks = 0; ks < 2; ++ks) {
      const int pb = (fr * 128 + ks * 64 + fq * 16) ^ xr;
      f16x8 pa0 = *(const f16x8*)(pw0 + pb);
      f16x8 pa1 = *(const f16x8*)(pw1 + pb);
      #pragma unroll
      for (int di = 0; di < 4; ++di) {
        f16x8 vf = *(const f16x8*)(bV + (di * 16 + fr) * 128
                                   + ((ks * 64 + fq * 16) ^ xr));
        o0[di] = mfma16(pa0, vf, o0[di]);
        o1[di] = mfma16(pa1, vf, o1[di]);
      }
    }
    __builtin_amdgcn_s_setprio(0);
  }

  // epilogue: divide by row sums (broadcast l to rows fq*4+r) and store
  #pragma unroll
  for (int st = 0; st < 2; ++st) {
    const f32x4* o = st ? o1 : o0;
    const float l = st ? l1 : l0;
    float linv[4];
    #pragma unroll
    for (int r = 0; r < 4; ++r)
      linv[r] = 1.f / __shfl(l, ((lane >> 4) << 2) + r, 64);
    #pragma unroll
    for (int di = 0; di < 4; ++di)
      #pragma unroll
      for (int r = 0; r < 4; ++r)
        AO[(long)(b * SEQ_ + qrow0 + st * 16 + fq * 4 + r) * DIM_
           + h * HD_ + di * 16 + fr] = (f16)(o[di][r] * linv[r]);
  }
}

// ---------------- launch ----------------
extern "C" void kernel_launch(void* const* d_in, const int* in_sizes, int n_in,
                              void* d_out, int out_size, void* d_ws, size_t ws_size,
                              hipStream_t stream) {
  const float* x  = (const float*)d_in[0];
  const float* wq = (const float*)d_in[1];
  const float* wk = (const float*)d_in[2];
  const float* wv = (const float*)d_in[3];
  const float* wo = (const float*)d_in[4];
  char* ws = (char*)d_ws;

  size_t off = 0;
  float* parts = (float*)ws;                off = 4096;
  f16* x_hi  = (f16*)(ws + off);            off += (size_t)MROWS_ * DIM_ * 2;
  f16* x_lo  = (f16*)(ws + off);            off += (size_t)MROWS_ * DIM_ * 2;
  f16* wq_t  = (f16*)(ws + off);            off += (size_t)DIM_ * DIM_ * 2;
  f16* wkv_t = (f16*)(ws + off);            off += (size_t)1024 * DIM_ * 2;  // contiguous after wq_t
  f16* wo_t  = (f16*)(ws + off);            off += (size_t)DIM_ * DIM_ * 2;
  f16* qhi   = (f16*)(ws + off);            off += (size_t)MROWS_ * DIM_ * 2;
  f16* qlo   = (f16*)(ws + off);            off += (size_t)MROWS_ * DIM_ * 2;
  f16* khi   = (f16*)(ws + off);            off += (size_t)MROWS_ * KVW_ * 2;
  f16* klo   = (f16*)(ws + off);            off += (size_t)MROWS_ * KVW_ * 2;
  f16* vtb   = (f16*)(ws + off);            off += (size_t)BATCH_ * 8 * 64 * SEQ_ * 2;
  f16* ao    = (f16*)(ws + off);            off += (size_t)MROWS_ * DIM_ * 2;

  // prep: |w| partials + x hi/lo split in one launch; ternarize reduces the
  // partials inline (deterministic fixed-order tree, no atomics anywhere)
  prep1<<<dim3(192, 6), dim3(256), 0, stream>>>(x, wq, wk, wv, wo,
                                                parts, x_hi, x_lo);
  ternarize4<<<dim3(192, 4), dim3(256), 0, stream>>>(
      wq, wk, wv, wo,
      (unsigned short*)wq_t, (unsigned short*)wkv_t,
      (unsigned short*)(wkv_t + (size_t)KVW_ * DIM_), (unsigned short*)wo_t,
      parts);

  // fused q+k+v projection: B = [wq_t ; wk_t ; wv_t] = 3072 rows (contiguous)
  gemm_qkv<<<dim3(384), dim3(256), 0, stream>>>(
      x_hi, x_lo, wq_t, qhi, qlo, khi, klo, vtb);

  attn_kernel<<<dim3(1024), dim3(256), 0, stream>>>(
      qhi, qlo, khi, klo, vtb, ao);

  gemm_o<<<dim3((DIM_ / 128) * (MROWS_ / 128)), dim3(256), 0, stream>>>(
      ao, wo_t, (float*)d_out);
}